// Round 3
// baseline (3750.211 us; speedup 1.0000x reference)
//
#include <hip/hip_runtime.h>
#include <stdint.h>

// ---------------- constants ----------------
static const size_t OFF_ATT = 20480;    // out: 1024*10*2
static const size_t OFF_H   = 122880;   // + att 1024*10*10
static const size_t OFF_C   = 385024;   // + h 2*1024*128

typedef _Float16 half2_t __attribute__((ext_vector_type(2)));

__device__ __forceinline__ float sigf(float x) { return 1.0f / (1.0f + __expf(-x)); }
// tanh(x) = 1 - 2/(e^{2x}+1); safe at +/-inf, ~1e-7 abs err.
__device__ __forceinline__ float tanhfast(float x) { return 1.0f - 2.0f / (__expf(2.0f * x) + 1.0f); }

__device__ __forceinline__ float fdot2(uint32_t w, uint32_t h, float acc) {
    return __builtin_amdgcn_fdot2(__builtin_bit_cast(half2_t, w), __builtin_bit_cast(half2_t, h), acc, false);
}

// ---------------- prep kernels ----------------
// W[R][C] -> Tm[C][R]
__global__ __launch_bounds__(256) void transpose_k(const float* __restrict__ W, float* __restrict__ Tm, int R, int C) {
    int idx = blockIdx.x * 256 + threadIdx.x;
    if (idx < R * C) {
        int r = idx / C, c = idx - r * C;
        Tm[(size_t)c * R + r] = W[idx];
    }
}

__global__ void bias_comb_k(const float* __restrict__ bih, const float* __restrict__ bhh,
                            float* __restrict__ b0, float* __restrict__ b1) {
    int i = blockIdx.x * 256 + threadIdx.x;
    if (i < 512) {
        b0[i] = bih[i] + bhh[i];
        b1[i] = bih[512 + i] + bhh[512 + i];
    }
}

// pack fp32 W[512][128] -> P[64][512] dwords; P[kp][j] = half2(W[j][2kp], W[j][2kp+1])
__global__ __launch_bounds__(256) void pack_w_k(const float* __restrict__ W, uint32_t* __restrict__ P) {
    int idx = blockIdx.x * 256 + threadIdx.x;   // 32768 total
    int kp = idx >> 9, j = idx & 511;
    half2_t h;
    h.x = (_Float16)W[j * 128 + 2 * kp];
    h.y = (_Float16)W[j * 128 + 2 * kp + 1];
    P[idx] = __builtin_bit_cast(uint32_t, h);
}

// ---------------- tiled GEMM: C = act(A[M,K] @ B[N,K]^T + bias[N]) ----------------
__global__ __launch_bounds__(256) void gemm_bias_act_k(const float* __restrict__ A, const float* __restrict__ Bm,
                                                       const float* __restrict__ bias, float* __restrict__ C,
                                                       int M, int N, int K, int relu) {
    __shared__ float As[16][68];
    __shared__ float Bs[16][68];
    int tid = threadIdx.x;
    int tx = tid & 15, ty = tid >> 4;
    int bm = blockIdx.y << 6, bn = blockIdx.x << 6;
    int lr = tid >> 2, lk = (tid & 3) << 2;
    float acc[4][4] = {};
    for (int k0 = 0; k0 < K; k0 += 16) {
        __syncthreads();
        float4 av = *(const float4*)(A + (size_t)(bm + lr) * K + k0 + lk);
        float4 bv = *(const float4*)(Bm + (size_t)(bn + lr) * K + k0 + lk);
        As[lk + 0][lr] = av.x; As[lk + 1][lr] = av.y; As[lk + 2][lr] = av.z; As[lk + 3][lr] = av.w;
        Bs[lk + 0][lr] = bv.x; Bs[lk + 1][lr] = bv.y; Bs[lk + 2][lr] = bv.z; Bs[lk + 3][lr] = bv.w;
        __syncthreads();
#pragma unroll
        for (int kk = 0; kk < 16; ++kk) {
            float a[4], b[4];
#pragma unroll
            for (int i = 0; i < 4; ++i) a[i] = As[kk][ty * 4 + i];
#pragma unroll
            for (int j = 0; j < 4; ++j) b[j] = Bs[kk][tx * 4 + j];
#pragma unroll
            for (int i = 0; i < 4; ++i)
#pragma unroll
                for (int j = 0; j < 4; ++j) acc[i][j] = fmaf(a[i], b[j], acc[i][j]);
        }
    }
#pragma unroll
    for (int i = 0; i < 4; ++i)
#pragma unroll
        for (int j = 0; j < 4; ++j) {
            float v = acc[i][j] + bias[bn + tx * 4 + j];
            if (relu) v = fmaxf(v, 0.0f);
            C[(size_t)(bm + ty * 4 + i) * N + bn + tx * 4 + j] = v;
        }
}

// ---------------- main sequential kernel ----------------
// 256 blocks x 1024 threads (16 waves, 4/SIMD). Block owns 4 batch rows.
// k-dimension split in HALF across thread groups: thread (kh, j) holds 96
// packed-fp16 weight dwords (one weight copy per CU = 393 KB of the 512 KB
// register file); partial gate sums combine via LDS. No AGPR round-trips.
__global__ __launch_bounds__(1024) void recurrent3_k(
    const float* __restrict__ xg0,      // [1024*10][512] = lstm_in@Wih0^T + bih0 + bhh0 (f32)
    const uint32_t* __restrict__ Wp0,   // packed Whh0 [64][512]
    const uint32_t* __restrict__ Wp1,   // packed Wih1
    const uint32_t* __restrict__ Wp2,   // packed Whh1
    const float* __restrict__ bias1,    // [512] bih1+bhh1
    const float* __restrict__ WqT, const float* __restrict__ bq,
    const float* __restrict__ WkT, const float* __restrict__ bk,
    const float* __restrict__ Wo1T, const float* __restrict__ bo1,
    const float* __restrict__ Wo2, const float* __restrict__ bo2,
    const float* __restrict__ gv, const float* __restrict__ uv,
    float* __restrict__ out) {
    __shared__ uint32_t hs0[64][4];     // packed h pairs: dword [kp][row] = (h[2kp],h[2kp+1])
    __shared__ uint32_t hs1[64][4];
    __shared__ float part[2][4][512];   // partial gate sums [kh][batch-row][gate col]
    __shared__ float Ms[4][10][128];
    __shared__ float qs[4][128];
    __shared__ float Kms[4][10][128];
    __shared__ float us[4][64];
    __shared__ float scs[4][10];

    const int tid = threadIdx.x;
    const int kh  = tid >> 9;           // k-half
    const int j   = tid & 511;          // gate column
    const int row = (tid >> 7) & 3;     // cell role (tid<512): batch row
    const int hj  = tid & 127;          //                      h index
    const int b0  = blockIdx.x << 2;
    const int b   = b0 + row;
    const int kb  = kh << 5;

    // weights -> registers (one copy per block, split across the two k-halves)
    uint32_t w0[32], w1[32], w2[32];
#pragma unroll
    for (int i = 0; i < 32; ++i) {
        w0[i] = Wp0[(kb + i) * 512 + j];
        w1[i] = Wp1[(kb + i) * 512 + j];
        w2[i] = Wp2[(kb + i) * 512 + j];
    }
    const float bs1 = (kh == 0) ? bias1[j] : 0.0f;

    // state init (gv/uv flat [2][1024][128] reinterpretation)
    float h0r = 0.f, h1r = 0.f, c0r = 0.f, c1r = 0.f;
    if (tid < 512) {
        h0r = gv[(size_t)b * 128 + hj];
        h1r = gv[131072 + (size_t)b * 128 + hj];
        c0r = uv[(size_t)b * 128 + hj];
        c1r = uv[131072 + (size_t)b * 128 + hj];
        int o = (hj >> 1) * 8 + row * 2 + (hj & 1);
        ((_Float16*)hs0)[o] = (_Float16)h0r;
        ((_Float16*)hs1)[o] = (_Float16)h1r;
    }
    __syncthreads();

    auto lstm_step = [&](int t) {
        // ---- layer 0 partial dots: my k-half of Whh0 @ h0 ----
        float a0 = 0.f, a1 = 0.f, a2 = 0.f, a3 = 0.f;
#pragma unroll
        for (int i = 0; i < 32; ++i) {
            uint4 hv = *(const uint4*)&hs0[kb + i][0];
            a0 = fdot2(w0[i], hv.x, a0);
            a1 = fdot2(w0[i], hv.y, a1);
            a2 = fdot2(w0[i], hv.z, a2);
            a3 = fdot2(w0[i], hv.w, a3);
        }
        part[kh][0][j] = a0; part[kh][1][j] = a1; part[kh][2][j] = a2; part[kh][3][j] = a3;
        __syncthreads();
        if (tid < 512) {    // cell 0: combine halves + xg0, update c0/h0
            const float* xgq = xg0 + ((size_t)b * 10 + t) * 512 + hj;
            float gi = part[0][row][hj]        + part[1][row][hj]        + xgq[0];
            float gf = part[0][row][128 + hj]  + part[1][row][128 + hj]  + xgq[128];
            float gg = part[0][row][256 + hj]  + part[1][row][256 + hj]  + xgq[256];
            float go = part[0][row][384 + hj]  + part[1][row][384 + hj]  + xgq[384];
            float cn = sigf(gf) * c0r + sigf(gi) * tanhfast(gg);
            float hn = sigf(go) * tanhfast(cn);
            c0r = cn; h0r = hn;
            ((_Float16*)hs0)[(hj >> 1) * 8 + row * 2 + (hj & 1)] = (_Float16)hn;
        }
        __syncthreads();
        // ---- layer 1 partial dots: my k-half of (Wih1 @ h0new + Whh1 @ h1) ----
        a0 = bs1; a1 = bs1; a2 = bs1; a3 = bs1;
#pragma unroll
        for (int i = 0; i < 32; ++i) {
            uint4 h0v = *(const uint4*)&hs0[kb + i][0];
            uint4 h1v = *(const uint4*)&hs1[kb + i][0];
            a0 = fdot2(w1[i], h0v.x, a0); a1 = fdot2(w1[i], h0v.y, a1);
            a2 = fdot2(w1[i], h0v.z, a2); a3 = fdot2(w1[i], h0v.w, a3);
            a0 = fdot2(w2[i], h1v.x, a0); a1 = fdot2(w2[i], h1v.y, a1);
            a2 = fdot2(w2[i], h1v.z, a2); a3 = fdot2(w2[i], h1v.w, a3);
        }
        part[kh][0][j] = a0; part[kh][1][j] = a1; part[kh][2][j] = a2; part[kh][3][j] = a3;
        __syncthreads();
        if (tid < 512) {    // cell 1
            float gi = part[0][row][hj]        + part[1][row][hj];
            float gf = part[0][row][128 + hj]  + part[1][row][128 + hj];
            float gg = part[0][row][256 + hj]  + part[1][row][256 + hj];
            float go = part[0][row][384 + hj]  + part[1][row][384 + hj];
            float cn = sigf(gf) * c1r + sigf(gi) * tanhfast(gg);
            float hn = sigf(go) * tanhfast(cn);
            c1r = cn; h1r = hn;
            ((_Float16*)hs1)[(hj >> 1) * 8 + row * 2 + (hj & 1)] = (_Float16)hn;
        }
        __syncthreads();
    };

    for (int r = 0; r < 10; ++r) {
        for (int hist = 0; hist <= r; ++hist) {
            const int t0 = (hist <= 1) ? 0 : hist;  // quirk: hist==1 reruns full prefix
            for (int t = t0; t <= r; ++t) lstm_step(t);
            if (tid < 512) Ms[row][hist][hj] = h1r;
        }
        __syncthreads();

        // ---------------- attention for round r ----------------
        if (tid < 512) {    // q[row][hj], K rows
            float aq = bq[hj];
            const float* mrow = &Ms[row][r][0];
            for (int k = 0; k < 128; ++k) aq = fmaf(mrow[k], WqT[k * 128 + hj], aq);
            qs[row][hj] = aq;
            for (int kk = 0; kk <= r; ++kk) {
                float ak = bk[hj];
                const float* m2 = &Ms[row][kk][0];
                for (int k = 0; k < 128; ++k) ak = fmaf(m2[k], WkT[k * 128 + hj], ak);
                Kms[row][kk][hj] = ak;
            }
        }
        __syncthreads();
        // raw scores: one thread per (row, kk)
        if (tid < 4 * (r + 1)) {
            int rw = tid / (r + 1), kk = tid - rw * (r + 1);
            float p = 0.f;
            const float* qp = &qs[rw][0];
            const float* kp_ = &Kms[rw][kk][0];
            for (int k = 0; k < 128; ++k) p = fmaf(qp[k], kp_[k], p);
            scs[rw][kk] = p * 0.088388347648318447f;   // 1/sqrt(128)
        }
        __syncthreads();
        // softmax + attention output (threads 0..39, single wave => lockstep)
        if (tid < 40) {
            int rw = tid / 10, jp = tid - rw * 10;
            float mx = -3.4e38f;
            for (int kk = 0; kk <= r; ++kk) mx = fmaxf(mx, scs[rw][kk]);
            float sum = 0.f;
            for (int kk = 0; kk <= r; ++kk) sum += __expf(scs[rw][kk] - mx);
            float inv = 1.0f / sum;
            float myv = (jp <= r) ? __expf(scs[rw][jp] - mx) * inv : 0.0f;
            if (jp <= r) scs[rw][jp] = myv;  // reads above precede store (lockstep)
            out[OFF_ATT + (size_t)(b0 + rw) * 100 + (size_t)r * 10 + jp] = (jp <= r) ? myv : -1.0f;
        }
        __syncthreads();
        // V head + weighted sum
        float o0 = 0.f, o1 = 0.f;
        for (int kk = 0; kk <= r; ++kk) {
            if (tid < 256) {
                int rw = tid >> 6, uj = tid & 63;
                float a = bo1[uj];
                const float* mrow = &Ms[rw][kk][0];
                for (int k = 0; k < 128; ++k) a = fmaf(mrow[k], Wo1T[k * 64 + uj], a);
                us[rw][uj] = fmaxf(a, 0.f);
            }
            __syncthreads();
            if (tid < 4) {
                float v0 = bo2[0], v1 = bo2[1];
                for (int k = 0; k < 64; ++k) {
                    float uu = us[tid][k];
                    v0 = fmaf(uu, Wo2[k], v0);
                    v1 = fmaf(uu, Wo2[64 + k], v1);
                }
                float mv = fmaxf(v0, v1);
                float lse = mv + __logf(__expf(v0 - mv) + __expf(v1 - mv));
                float s = scs[tid][kk];
                o0 = fmaf(s, v0 - lse, o0);
                o1 = fmaf(s, v1 - lse, o1);
            }
            __syncthreads();
        }
        if (tid < 4) {
            out[(size_t)(b0 + tid) * 20 + r * 2 + 0] = o0;
            out[(size_t)(b0 + tid) * 20 + r * 2 + 1] = o1;
        }
    }

    // final h, c
    if (tid < 512) {
        out[OFF_H + (size_t)b * 128 + hj]          = h0r;
        out[OFF_H + 131072 + (size_t)b * 128 + hj] = h1r;
        out[OFF_C + (size_t)b * 128 + hj]          = c0r;
        out[OFF_C + 131072 + (size_t)b * 128 + hj] = c1r;
    }
}

// ---------------- launch ----------------
extern "C" void kernel_launch(void* const* d_in, const int* in_sizes, int n_in,
                              void* d_out, int out_size, void* d_ws, size_t ws_size,
                              hipStream_t stream) {
    const float* input_vec = (const float*)d_in[0];
    const float* gv    = (const float*)d_in[1];
    const float* uv    = (const float*)d_in[2];
    const float* W_in1 = (const float*)d_in[3];
    const float* b_in1 = (const float*)d_in[4];
    const float* W_in2 = (const float*)d_in[5];
    const float* b_in2 = (const float*)d_in[6];
    const float* Wq    = (const float*)d_in[7];
    const float* bq    = (const float*)d_in[8];
    const float* Wk    = (const float*)d_in[9];
    const float* bk    = (const float*)d_in[10];
    const float* Wih   = (const float*)d_in[11];
    const float* Whh   = (const float*)d_in[12];
    const float* bih   = (const float*)d_in[13];
    const float* bhh   = (const float*)d_in[14];
    const float* Wo1   = (const float*)d_in[15];
    const float* bo1   = (const float*)d_in[16];
    const float* Wo2   = (const float*)d_in[17];
    const float* bo2   = (const float*)d_in[18];
    float* out = (float*)d_out;
    float* ws  = (float*)d_ws;

    // workspace layout (float units). tmp1 and xg0 share region 0.
    float* tmp1    = ws + 0;          // [10240][1024]
    float* xg0     = ws + 0;          // [10240][512]
    float* lstm_in = ws + 10485760;   // [10240][128]
    uint32_t* Wp0  = (uint32_t*)(ws + 11796480);   // [64][512]
    uint32_t* Wp1  = (uint32_t*)(ws + 11829248);
    uint32_t* Wp2  = (uint32_t*)(ws + 11862016);
    float* WqT     = ws + 11894784;   // [128][128]
    float* WkT     = ws + 11911168;
    float* Wo1T    = ws + 11927552;   // [128][64]
    float* bias0c  = ws + 11935744;   // [512]
    float* bias1c  = ws + 11936256;   // [512]

    pack_w_k<<<128, 256, 0, stream>>>(Whh, Wp0);            // layer-0 Whh
    pack_w_k<<<128, 256, 0, stream>>>(Wih + 65536, Wp1);    // layer-1 Wih
    pack_w_k<<<128, 256, 0, stream>>>(Whh + 65536, Wp2);    // layer-1 Whh
    transpose_k<<<64, 256, 0, stream>>>(Wq, WqT, 128, 128);
    transpose_k<<<64, 256, 0, stream>>>(Wk, WkT, 128, 128);
    transpose_k<<<32, 256, 0, stream>>>(Wo1, Wo1T, 64, 128);
    bias_comb_k<<<2, 256, 0, stream>>>(bih, bhh, bias0c, bias1c);

    // input MLP + layer-0 input-gate precompute (fp32)
    gemm_bias_act_k<<<dim3(16, 160), 256, 0, stream>>>(input_vec, W_in1, b_in1, tmp1, 10240, 1024, 512, 1);
    gemm_bias_act_k<<<dim3(2, 160), 256, 0, stream>>>(tmp1, W_in2, b_in2, lstm_in, 10240, 128, 1024, 1);
    gemm_bias_act_k<<<dim3(8, 160), 256, 0, stream>>>(lstm_in, Wih, bias0c, xg0, 10240, 512, 128, 0);

    recurrent3_k<<<256, 1024, 0, stream>>>(xg0, Wp0, Wp1, Wp2, bias1c,
                                           WqT, bq, WkT, bk, Wo1T, bo1, Wo2, bo2,
                                           gv, uv, out);
}

// Round 4
// 2088.215 us; speedup vs baseline: 1.7959x; 1.7959x over previous
//
#include <hip/hip_runtime.h>
#include <stdint.h>

// ---------------- constants ----------------
static const size_t OFF_ATT = 20480;    // out: 1024*10*2
static const size_t OFF_H   = 122880;   // + att 1024*10*10
static const size_t OFF_C   = 385024;   // + h 2*1024*128

typedef _Float16 f16;
typedef f16 f16x8 __attribute__((ext_vector_type(8)));
typedef float f32x4 __attribute__((ext_vector_type(4)));

__device__ __forceinline__ float sigf(float x) { return 1.0f / (1.0f + __expf(-x)); }
// tanh(x) = 1 - 2/(e^{2x}+1); safe at +/-inf, ~1e-7 abs err.
__device__ __forceinline__ float tanhfast(float x) { return 1.0f - 2.0f / (__expf(2.0f * x) + 1.0f); }

#define MFMA16(a, b, c) __builtin_amdgcn_mfma_f32_16x16x32_f16((a), (b), (c), 0, 0, 0)

// ---------------- prep kernels ----------------
__global__ void bias_comb_k(const float* __restrict__ bih, const float* __restrict__ bhh,
                            float* __restrict__ b0, float* __restrict__ b1) {
    int i = blockIdx.x * 256 + threadIdx.x;
    if (i < 512) {
        b0[i] = bih[i] + bhh[i];
        b1[i] = bih[512 + i] + bhh[512 + i];
    }
}

// pack f32 W[N][K] (row-major) into f16 B-fragment-linear buffer:
// out[((nt*(K/32)+kt)*64 + lane)*8 + i] = W[nt*16 + (lane&15)][kt*32 + (lane>>4)*8 + i]
__global__ __launch_bounds__(256) void pack_frag_k(const float* __restrict__ W, f16* __restrict__ out,
                                                   int N, int K) {
    int idx = blockIdx.x * 256 + threadIdx.x;
    if (idx >= N * K) return;
    int i = idx & 7, l = (idx >> 3) & 63, rest = idx >> 9;
    int KT = K >> 5;
    int kt = rest % KT, nt = rest / KT;
    int n = nt * 16 + (l & 15);
    int k = kt * 32 + (l >> 4) * 8 + i;
    out[idx] = (f16)W[n * K + k];
}

// xg0[b][t][512] -> xgr[blk][t][col][row16]  (frag-friendly C-init layout)
__global__ __launch_bounds__(256) void reshape_xg_k(const float* __restrict__ xg0, float* __restrict__ xgr) {
    int idx = blockIdx.x * 256 + threadIdx.x;     // 64*10*512*16 = 5242880
    int row16 = idx & 15;
    int col   = (idx >> 4) & 511;
    int tb    = idx >> 13;         // blk*10 + t
    int t     = tb % 10, blk = tb / 10;
    xgr[idx] = xg0[(((size_t)(blk * 16 + row16) * 10 + t) << 9) + col];
}

// ---------------- tiled GEMM: C = act(A[M,K] @ B[N,K]^T + bias[N]) ----------------
__global__ __launch_bounds__(256) void gemm_bias_act_k(const float* __restrict__ A, const float* __restrict__ Bm,
                                                       const float* __restrict__ bias, float* __restrict__ C,
                                                       int M, int N, int K, int relu) {
    __shared__ float As[16][68];
    __shared__ float Bs[16][68];
    int tid = threadIdx.x;
    int tx = tid & 15, ty = tid >> 4;
    int bm = blockIdx.y << 6, bn = blockIdx.x << 6;
    int lr = tid >> 2, lk = (tid & 3) << 2;
    float acc[4][4] = {};
    for (int k0 = 0; k0 < K; k0 += 16) {
        __syncthreads();
        float4 av = *(const float4*)(A + (size_t)(bm + lr) * K + k0 + lk);
        float4 bv = *(const float4*)(Bm + (size_t)(bn + lr) * K + k0 + lk);
        As[lk + 0][lr] = av.x; As[lk + 1][lr] = av.y; As[lk + 2][lr] = av.z; As[lk + 3][lr] = av.w;
        Bs[lk + 0][lr] = bv.x; Bs[lk + 1][lr] = bv.y; Bs[lk + 2][lr] = bv.z; Bs[lk + 3][lr] = bv.w;
        __syncthreads();
#pragma unroll
        for (int kk = 0; kk < 16; ++kk) {
            float a[4], b[4];
#pragma unroll
            for (int i = 0; i < 4; ++i) a[i] = As[kk][ty * 4 + i];
#pragma unroll
            for (int j = 0; j < 4; ++j) b[j] = Bs[kk][tx * 4 + j];
#pragma unroll
            for (int i = 0; i < 4; ++i)
#pragma unroll
                for (int j = 0; j < 4; ++j) acc[i][j] = fmaf(a[i], b[j], acc[i][j]);
        }
    }
#pragma unroll
    for (int i = 0; i < 4; ++i)
#pragma unroll
        for (int j = 0; j < 4; ++j) {
            float v = acc[i][j] + bias[bn + tx * 4 + j];
            if (relu) v = fmaxf(v, 0.0f);
            C[(size_t)(bm + ty * 4 + i) * N + bn + tx * 4 + j] = v;
        }
}

// ---------------- main MFMA recurrent kernel ----------------
// 64 blocks x 512 threads (8 waves). Block owns 16 batch rows. Wave w owns gate
// columns [16w,16w+16) of each gate quadrant (N-tiles {w,8+w,16+w,24+w}), so the
// i/f/g/o quadruple for a cell is lane-local after MFMA (C/D: col=lane&15,
// row=(lane>>4)*4+reg — HW-verified mapping). Weights = 48 B-frags in regs/AGPRs.
__global__ __launch_bounds__(512, 2) void recurrent_mfma_k(
    const float* __restrict__ xgr,     // [blk][t][col512][row16] f32
    const f16* __restrict__ Wf,        // 3 mats x 512x128 f16 frag-linear (Whh0, Wih1, Whh1)
    const float* __restrict__ bias1,   // [512] bih1+bhh1
    const f16* __restrict__ Wqf, const float* __restrict__ bq,
    const f16* __restrict__ Wkf, const float* __restrict__ bk,
    const f16* __restrict__ Wo1f, const float* __restrict__ bo1,
    const float* __restrict__ Wo2, const float* __restrict__ bo2,
    const float* __restrict__ gv, const float* __restrict__ uv,
    float* __restrict__ out) {
    __shared__ __align__(16) f16 hA0[2][2048];    // 16 rows x 128 f16, XOR-swizzled, dbl-buffered
    __shared__ __align__(16) f16 hA1[2][2048];
    __shared__ __align__(16) f16 Msh[10][2048];   // M history, same layout per hist
    __shared__ __align__(16) f16 Kms[10][16 * 136];
    __shared__ __align__(16) float qsm[16 * 132];
    __shared__ __align__(16) float us[16 * 68];
    __shared__ float scs[16][10];
    __shared__ float wo2s[130];

    const int tid  = threadIdx.x;
    const int lane = tid & 63;
    const int w    = tid >> 6;        // wave id 0..7
    const int ml   = lane & 15;       // tile row (A/m) / tile col (B/n, D col)
    const int qh   = lane >> 4;       // lane quad -> k-group / D row group
    const int blk  = blockIdx.x;
    const int b0   = blk << 4;

    if (tid < 128) wo2s[tid] = Wo2[tid];
    if (tid < 2)   wo2s[128 + tid] = bo2[tid];

    // ---- persistent weight fragments (registers/AGPRs) ----
    f16x8 B0[4][4], B1[4][4], B2[4][4];
#pragma unroll
    for (int g = 0; g < 4; ++g)
#pragma unroll
        for (int kt = 0; kt < 4; ++kt) {
            int nt = g * 8 + w;
            B0[g][kt] = *(const f16x8*)(Wf +           (((nt * 4 + kt) * 64 + lane) << 3));
            B1[g][kt] = *(const f16x8*)(Wf +  65536 + (((nt * 4 + kt) * 64 + lane) << 3));
            B2[g][kt] = *(const f16x8*)(Wf + 131072 + (((nt * 4 + kt) * 64 + lane) << 3));
        }
    float bs1v[4];
#pragma unroll
    for (int g = 0; g < 4; ++g) bs1v[g] = bias1[g * 128 + w * 16 + ml];
    const float bqv  = bq[w * 16 + ml];
    const float bkv  = bk[w * 16 + ml];
    const float bo1v = (w < 4) ? bo1[w * 16 + ml] : 0.0f;

    // ---- state init ----
    float h0v[4], h1v[4], c0v[4], c1v[4];
#pragma unroll
    for (int r4 = 0; r4 < 4; ++r4) {
        int row = qh * 4 + r4;
        int b = b0 + row, hj = w * 16 + ml;
        h0v[r4] = gv[(size_t)b * 128 + hj];
        h1v[r4] = gv[131072 + (size_t)b * 128 + hj];
        c0v[r4] = uv[(size_t)b * 128 + hj];
        c1v[r4] = uv[131072 + (size_t)b * 128 + hj];
        int ke = hj ^ ((row & 7) << 3);
        hA0[0][row * 128 + ke] = (f16)h0v[r4];
        hA1[0][row * 128 + ke] = (f16)h1v[r4];
    }
    int p = 0;
    __syncthreads();

    // A-frag read: lane reads A[m=ml][k = kt*32 + qh*8 .. +8] from swizzled tile
    auto readA = [&](const f16* base, int kt) -> f16x8 {
        int e = ml * 128 + (((kt << 5) + (qh << 3)) ^ ((ml & 7) << 3));
        return *(const f16x8*)(base + e);
    };

    auto lstm_step = [&](int t) {
        // ---------- layer 0: gates = h0 @ Whh0^T + xg0 ----------
        f32x4 C0, C1, C2, C3;
        {
            const float* xb = xgr + ((((size_t)blk * 10 + t) << 9) << 4);
            int coff = w * 16 + ml;
            C0 = *(const f32x4*)(xb + ((coff      ) << 4) + qh * 4);
            C1 = *(const f32x4*)(xb + ((coff + 128) << 4) + qh * 4);
            C2 = *(const f32x4*)(xb + ((coff + 256) << 4) + qh * 4);
            C3 = *(const f32x4*)(xb + ((coff + 384) << 4) + qh * 4);
        }
        const f16* h0p = &hA0[p][0];
#pragma unroll
        for (int kt = 0; kt < 4; ++kt) {
            f16x8 a = readA(h0p, kt);
            C0 = MFMA16(a, B0[0][kt], C0);
            C1 = MFMA16(a, B0[1][kt], C1);
            C2 = MFMA16(a, B0[2][kt], C2);
            C3 = MFMA16(a, B0[3][kt], C3);
        }
        f16* h0n = &hA0[p ^ 1][0];
#pragma unroll
        for (int r4 = 0; r4 < 4; ++r4) {
            float cn = sigf(C1[r4]) * c0v[r4] + sigf(C0[r4]) * tanhfast(C2[r4]);
            float hn = sigf(C3[r4]) * tanhfast(cn);
            c0v[r4] = cn; h0v[r4] = hn;
            int row = qh * 4 + r4;
            h0n[row * 128 + ((w * 16 + ml) ^ ((row & 7) << 3))] = (f16)hn;
        }
        __syncthreads();
        // ---------- layer 1: gates = h0new @ Wih1^T + h1 @ Whh1^T + bias1 ----------
        C0 = f32x4{bs1v[0], bs1v[0], bs1v[0], bs1v[0]};
        C1 = f32x4{bs1v[1], bs1v[1], bs1v[1], bs1v[1]};
        C2 = f32x4{bs1v[2], bs1v[2], bs1v[2], bs1v[2]};
        C3 = f32x4{bs1v[3], bs1v[3], bs1v[3], bs1v[3]};
#pragma unroll
        for (int kt = 0; kt < 4; ++kt) {
            f16x8 a = readA(h0n, kt);
            C0 = MFMA16(a, B1[0][kt], C0);
            C1 = MFMA16(a, B1[1][kt], C1);
            C2 = MFMA16(a, B1[2][kt], C2);
            C3 = MFMA16(a, B1[3][kt], C3);
        }
        const f16* h1p = &hA1[p][0];
#pragma unroll
        for (int kt = 0; kt < 4; ++kt) {
            f16x8 a = readA(h1p, kt);
            C0 = MFMA16(a, B2[0][kt], C0);
            C1 = MFMA16(a, B2[1][kt], C1);
            C2 = MFMA16(a, B2[2][kt], C2);
            C3 = MFMA16(a, B2[3][kt], C3);
        }
        f16* h1n = &hA1[p ^ 1][0];
#pragma unroll
        for (int r4 = 0; r4 < 4; ++r4) {
            float cn = sigf(C1[r4]) * c1v[r4] + sigf(C0[r4]) * tanhfast(C2[r4]);
            float hn = sigf(C3[r4]) * tanhfast(cn);
            c1v[r4] = cn; h1v[r4] = hn;
            int row = qh * 4 + r4;
            h1n[row * 128 + ((w * 16 + ml) ^ ((row & 7) << 3))] = (f16)hn;
        }
        p ^= 1;
        __syncthreads();
    };

    for (int r = 0; r < 10; ++r) {
        for (int hist = 0; hist <= r; ++hist) {
            const int t0 = (hist <= 1) ? 0 : hist;  // quirk: hist==1 reruns full prefix
            for (int t = t0; t <= r; ++t) lstm_step(t);
#pragma unroll
            for (int r4 = 0; r4 < 4; ++r4) {   // Ms[hist] = h1
                int row = qh * 4 + r4;
                Msh[hist][row * 128 + ((w * 16 + ml) ^ ((row & 7) << 3))] = (f16)h1v[r4];
            }
        }
        __syncthreads();

        // ---------------- attention for round r ----------------
        {   // K rows (all 8 waves, n-tile = w), then Q
            f16x8 Bk[4];
#pragma unroll
            for (int kt = 0; kt < 4; ++kt) Bk[kt] = *(const f16x8*)(Wkf + (((w * 4 + kt) * 64 + lane) << 3));
            for (int kk = 0; kk <= r; ++kk) {
                f32x4 C = f32x4{bkv, bkv, bkv, bkv};
#pragma unroll
                for (int kt = 0; kt < 4; ++kt) C = MFMA16(readA(&Msh[kk][0], kt), Bk[kt], C);
#pragma unroll
                for (int r4 = 0; r4 < 4; ++r4) Kms[kk][(qh * 4 + r4) * 136 + w * 16 + ml] = (f16)C[r4];
            }
            f16x8 Bq[4];
#pragma unroll
            for (int kt = 0; kt < 4; ++kt) Bq[kt] = *(const f16x8*)(Wqf + (((w * 4 + kt) * 64 + lane) << 3));
            f32x4 C = f32x4{bqv, bqv, bqv, bqv};
#pragma unroll
            for (int kt = 0; kt < 4; ++kt) C = MFMA16(readA(&Msh[r][0], kt), Bq[kt], C);
#pragma unroll
            for (int r4 = 0; r4 < 4; ++r4) qsm[(qh * 4 + r4) * 132 + w * 16 + ml] = C[r4];
        }
        __syncthreads();
        // raw scores: thread per (row, kk)
        if (tid < 16 * (r + 1)) {
            int row = tid & 15, kk = tid >> 4;
            const float* qp = qsm + row * 132;
            const f16* kp = &Kms[kk][row * 136];
            float pacc = 0.f;
            for (int k = 0; k < 128; ++k) pacc += qp[k] * (float)kp[k];
            scs[row][kk] = pacc * 0.088388347648318447f;   // 1/sqrt(128)
        }
        __syncthreads();
        if (tid < 16) {   // softmax per row, probs in place
            float mx = -3.4e38f;
            for (int kk = 0; kk <= r; ++kk) mx = fmaxf(mx, scs[tid][kk]);
            float sum = 0.f;
            for (int kk = 0; kk <= r; ++kk) sum += __expf(scs[tid][kk] - mx);
            float inv = 1.0f / sum;
            for (int kk = 0; kk <= r; ++kk) scs[tid][kk] = __expf(scs[tid][kk] - mx) * inv;
        }
        __syncthreads();
        if (tid < 160) {  // attention output with -1 padding
            int row = tid / 10, jp = tid - row * 10;
            out[OFF_ATT + (size_t)(b0 + row) * 100 + (size_t)r * 10 + jp] = (jp <= r) ? scs[row][jp] : -1.0f;
        }
        // ---- V head: u = relu(Ms @ Wo1^T + bo1), v = u @ Wo2^T + bo2, logsoftmax ----
        float oa0 = 0.f, oa1 = 0.f;
        f16x8 Bo[4];
        if (w < 4) {
#pragma unroll
            for (int kt = 0; kt < 4; ++kt) Bo[kt] = *(const f16x8*)(Wo1f + (((w * 4 + kt) * 64 + lane) << 3));
        }
        for (int kk = 0; kk <= r; ++kk) {
            if (w < 4) {
                f32x4 C = f32x4{bo1v, bo1v, bo1v, bo1v};
#pragma unroll
                for (int kt = 0; kt < 4; ++kt) C = MFMA16(readA(&Msh[kk][0], kt), Bo[kt], C);
#pragma unroll
                for (int r4 = 0; r4 < 4; ++r4) us[(qh * 4 + r4) * 68 + w * 16 + ml] = fmaxf(C[r4], 0.f);
            }
            __syncthreads();
            if (tid < 16) {
                float v0 = wo2s[128], v1 = wo2s[129];
                const float* up = us + tid * 68;
                for (int k = 0; k < 64; ++k) {
                    float uu = up[k];
                    v0 = fmaf(uu, wo2s[k], v0);
                    v1 = fmaf(uu, wo2s[64 + k], v1);
                }
                float mv = fmaxf(v0, v1);
                float lse = mv + __logf(__expf(v0 - mv) + __expf(v1 - mv));
                float pp = scs[tid][kk];
                oa0 = fmaf(pp, v0 - lse, oa0);
                oa1 = fmaf(pp, v1 - lse, oa1);
            }
            __syncthreads();
        }
        if (tid < 16) {
            out[(size_t)(b0 + tid) * 20 + r * 2 + 0] = oa0;
            out[(size_t)(b0 + tid) * 20 + r * 2 + 1] = oa1;
        }
    }

    // final h, c (f32 register copies)
#pragma unroll
    for (int r4 = 0; r4 < 4; ++r4) {
        int b = b0 + qh * 4 + r4, hj = w * 16 + ml;
        out[OFF_H + (size_t)b * 128 + hj]          = h0v[r4];
        out[OFF_H + 131072 + (size_t)b * 128 + hj] = h1v[r4];
        out[OFF_C + (size_t)b * 128 + hj]          = c0v[r4];
        out[OFF_C + 131072 + (size_t)b * 128 + hj] = c1v[r4];
    }
}

// ---------------- launch ----------------
extern "C" void kernel_launch(void* const* d_in, const int* in_sizes, int n_in,
                              void* d_out, int out_size, void* d_ws, size_t ws_size,
                              hipStream_t stream) {
    const float* input_vec = (const float*)d_in[0];
    const float* gv    = (const float*)d_in[1];
    const float* uv    = (const float*)d_in[2];
    const float* W_in1 = (const float*)d_in[3];
    const float* b_in1 = (const float*)d_in[4];
    const float* W_in2 = (const float*)d_in[5];
    const float* b_in2 = (const float*)d_in[6];
    const float* Wq    = (const float*)d_in[7];
    const float* bq    = (const float*)d_in[8];
    const float* Wk    = (const float*)d_in[9];
    const float* bk    = (const float*)d_in[10];
    const float* Wih   = (const float*)d_in[11];
    const float* Whh   = (const float*)d_in[12];
    const float* bih   = (const float*)d_in[13];
    const float* bhh   = (const float*)d_in[14];
    const float* Wo1   = (const float*)d_in[15];
    const float* bo1   = (const float*)d_in[16];
    const float* Wo2   = (const float*)d_in[17];
    const float* bo2   = (const float*)d_in[18];
    float* out = (float*)d_out;
    float* ws  = (float*)d_ws;

    // workspace layout (float units)
    float* tmp1    = ws + 0;           // [10240][1024] (dead after gemm2)
    float* xg0     = ws + 0;           // [10240][512]  (gemm3 out, over tmp1)
    float* xgr     = ws + 5242880;     // [64][10][512][16] (inside old tmp1 tail)
    float* lstm_in = ws + 10485760;    // [10240][128]
    f16*   Wf      = (f16*)(ws + 11796480);   // 3 x 65536 f16
    f16*   Wqf     = (f16*)(ws + 11894784);   // 16384 f16
    f16*   Wkf     = (f16*)(ws + 11902976);
    f16*   Wo1f    = (f16*)(ws + 11911168);   // 8192 f16
    float* bias1c  = ws + 11915264;    // [512]
    float* bias0c  = ws + 11915776;    // [512]

    // weight fragment packing + bias combine
    pack_frag_k<<<256, 256, 0, stream>>>(Whh,          Wf,           512, 128); // Whh0
    pack_frag_k<<<256, 256, 0, stream>>>(Wih + 65536,  Wf + 65536,   512, 128); // Wih1
    pack_frag_k<<<256, 256, 0, stream>>>(Whh + 65536,  Wf + 131072,  512, 128); // Whh1
    pack_frag_k<<<64,  256, 0, stream>>>(Wq,  Wqf,  128, 128);
    pack_frag_k<<<64,  256, 0, stream>>>(Wk,  Wkf,  128, 128);
    pack_frag_k<<<32,  256, 0, stream>>>(Wo1, Wo1f, 64,  128);
    bias_comb_k<<<2, 256, 0, stream>>>(bih, bhh, bias0c, bias1c);

    // input MLP + layer-0 input-gate precompute (fp32), then frag-layout reshape
    gemm_bias_act_k<<<dim3(16, 160), 256, 0, stream>>>(input_vec, W_in1, b_in1, tmp1, 10240, 1024, 512, 1);
    gemm_bias_act_k<<<dim3(2, 160), 256, 0, stream>>>(tmp1, W_in2, b_in2, lstm_in, 10240, 128, 1024, 1);
    gemm_bias_act_k<<<dim3(8, 160), 256, 0, stream>>>(lstm_in, Wih, bias0c, xg0, 10240, 512, 128, 0);
    reshape_xg_k<<<20480, 256, 0, stream>>>(xg0, xgr);

    recurrent_mfma_k<<<64, 512, 0, stream>>>(xgr, Wf, bias1c,
                                             Wqf, bq, Wkf, bk, Wo1f, bo1, Wo2, bo2,
                                             gv, uv, out);
}

// Round 5
// 1792.030 us; speedup vs baseline: 2.0927x; 1.1653x over previous
//
#include <hip/hip_runtime.h>
#include <stdint.h>

// ---------------- constants ----------------
static const size_t OFF_ATT = 20480;    // out: 1024*10*2
static const size_t OFF_H   = 122880;   // + att 1024*10*10
static const size_t OFF_C   = 385024;   // + h 2*1024*128

typedef _Float16 f16;
typedef f16 f16x8 __attribute__((ext_vector_type(8)));
typedef float f32x4 __attribute__((ext_vector_type(4)));

__device__ __forceinline__ float sigf(float x) { return 1.0f / (1.0f + __expf(-x)); }
// tanh(x) = 1 - 2/(e^{2x}+1); safe at +/-inf, ~1e-7 abs err.
__device__ __forceinline__ float tanhfast(float x) { return 1.0f - 2.0f / (__expf(2.0f * x) + 1.0f); }

#define MFMA16(a, b, c) __builtin_amdgcn_mfma_f32_16x16x32_f16((a), (b), (c), 0, 0, 0)

// ---------------- prep kernels ----------------
__global__ void bias_comb_k(const float* __restrict__ bih, const float* __restrict__ bhh,
                            float* __restrict__ b0, float* __restrict__ b1) {
    int i = blockIdx.x * 256 + threadIdx.x;
    if (i < 512) {
        b0[i] = bih[i] + bhh[i];
        b1[i] = bih[512 + i] + bhh[512 + i];
    }
}

// pack f32 W[N][K] (row-major) into f16 B-fragment-linear buffer:
// out[((nt*(K/32)+kt)*64 + lane)*8 + i] = W[nt*16 + (lane&15)][kt*32 + (lane>>4)*8 + i]
__global__ __launch_bounds__(256) void pack_frag_k(const float* __restrict__ W, f16* __restrict__ out,
                                                   int N, int K) {
    int idx = blockIdx.x * 256 + threadIdx.x;
    if (idx >= N * K) return;
    int i = idx & 7, l = (idx >> 3) & 63, rest = idx >> 9;
    int KT = K >> 5;
    int kt = rest % KT, nt = rest / KT;
    int n = nt * 16 + (l & 15);
    int k = kt * 32 + (l >> 4) * 8 + i;
    out[idx] = (f16)W[n * K + k];
}

// xg0[b][t][512] -> xgr[blk][t][col][row16]  (frag-friendly C-init layout)
__global__ __launch_bounds__(256) void reshape_xg_k(const float* __restrict__ xg0, float* __restrict__ xgr) {
    int idx = blockIdx.x * 256 + threadIdx.x;     // 64*10*512*16 = 5242880
    int row16 = idx & 15;
    int col   = (idx >> 4) & 511;
    int tb    = idx >> 13;         // blk*10 + t
    int t     = tb % 10, blk = tb / 10;
    xgr[idx] = xg0[(((size_t)(blk * 16 + row16) * 10 + t) << 9) + col];
}

// ---------------- tiled GEMM: C = act(A[M,K] @ B[N,K]^T + bias[N]) ----------------
__global__ __launch_bounds__(256) void gemm_bias_act_k(const float* __restrict__ A, const float* __restrict__ Bm,
                                                       const float* __restrict__ bias, float* __restrict__ C,
                                                       int M, int N, int K, int relu) {
    __shared__ float As[16][68];
    __shared__ float Bs[16][68];
    int tid = threadIdx.x;
    int tx = tid & 15, ty = tid >> 4;
    int bm = blockIdx.y << 6, bn = blockIdx.x << 6;
    int lr = tid >> 2, lk = (tid & 3) << 2;
    float acc[4][4] = {};
    for (int k0 = 0; k0 < K; k0 += 16) {
        __syncthreads();
        float4 av = *(const float4*)(A + (size_t)(bm + lr) * K + k0 + lk);
        float4 bv = *(const float4*)(Bm + (size_t)(bn + lr) * K + k0 + lk);
        As[lk + 0][lr] = av.x; As[lk + 1][lr] = av.y; As[lk + 2][lr] = av.z; As[lk + 3][lr] = av.w;
        Bs[lk + 0][lr] = bv.x; Bs[lk + 1][lr] = bv.y; Bs[lk + 2][lr] = bv.z; Bs[lk + 3][lr] = bv.w;
        __syncthreads();
#pragma unroll
        for (int kk = 0; kk < 16; ++kk) {
            float a[4], b[4];
#pragma unroll
            for (int i = 0; i < 4; ++i) a[i] = As[kk][ty * 4 + i];
#pragma unroll
            for (int j = 0; j < 4; ++j) b[j] = Bs[kk][tx * 4 + j];
#pragma unroll
            for (int i = 0; i < 4; ++i)
#pragma unroll
                for (int j = 0; j < 4; ++j) acc[i][j] = fmaf(a[i], b[j], acc[i][j]);
        }
    }
#pragma unroll
    for (int i = 0; i < 4; ++i)
#pragma unroll
        for (int j = 0; j < 4; ++j) {
            float v = acc[i][j] + bias[bn + tx * 4 + j];
            if (relu) v = fmaxf(v, 0.0f);
            C[(size_t)(bm + ty * 4 + i) * N + bn + tx * 4 + j] = v;
        }
}

// ---------------- main MFMA recurrent kernel ----------------
// 64 blocks x 512 threads (8 waves). Block owns 16 batch rows. Wave w owns gate
// columns [16w,16w+16) of each gate quadrant (N-tiles {w,8+w,16+w,24+w}).
// Weights are STREAMED from L2 each step (393 KB/block/step; weights are
// L2-resident since identical across steps & blocks). The weight base pointer
// is re-read from LDS each step so LICM cannot hoist the (address-invariant)
// frag loads into persistent registers -> no spill (R3/R4 lesson).
__global__ __launch_bounds__(512, 2) void recurrent_mfma_k(
    const float* __restrict__ xgr,     // [blk][t][col512][row16] f32
    const f16* __restrict__ Wf,        // 3 mats x 512x128 f16 frag-linear (Whh0, Wih1, Whh1)
    const float* __restrict__ bias1,   // [512] bih1+bhh1
    const f16* __restrict__ Wqf, const float* __restrict__ bq,
    const f16* __restrict__ Wkf, const float* __restrict__ bk,
    const f16* __restrict__ Wo1f, const float* __restrict__ bo1,
    const float* __restrict__ Wo2, const float* __restrict__ bo2,
    const float* __restrict__ gv, const float* __restrict__ uv,
    float* __restrict__ out) {
    __shared__ __align__(16) f16 hA0[2][2048];    // 16 rows x 128 f16, XOR-swizzled, dbl-buffered
    __shared__ __align__(16) f16 hA1[2][2048];
    __shared__ __align__(16) f16 Msh[10][2048];   // M history, same layout per hist
    __shared__ __align__(16) f16 Kms[10][16 * 136];
    __shared__ __align__(16) float qsm[16 * 132];
    __shared__ __align__(16) float us[16 * 68];
    __shared__ float scs[16][10];
    __shared__ float wo2s[130];
    __shared__ unsigned long long wbase_s;        // LICM blocker (re-read per step)

    const int tid  = threadIdx.x;
    const int lane = tid & 63;
    const int w    = tid >> 6;        // wave id 0..7
    const int ml   = lane & 15;       // tile row (A/m) / tile col (B/n, D col)
    const int qh   = lane >> 4;       // lane quad -> k-group / D row group
    const int blk  = blockIdx.x;
    const int b0   = blk << 4;

    if (tid < 128) wo2s[tid] = Wo2[tid];
    if (tid < 2)   wo2s[128 + tid] = bo2[tid];
    if (tid == 0)  wbase_s = (unsigned long long)(uintptr_t)Wf;

    float bs1v[4];
#pragma unroll
    for (int g = 0; g < 4; ++g) bs1v[g] = bias1[g * 128 + w * 16 + ml];
    const float bqv  = bq[w * 16 + ml];
    const float bkv  = bk[w * 16 + ml];
    const float bo1v = (w < 4) ? bo1[w * 16 + ml] : 0.0f;

    // per-wave/lane constant offset into the frag-linear weight buffers:
    // frag(nt, kt) at ((nt*4 + kt)*64 + lane)*8, nt = g*8 + w
    const int fo = (w * 4) * 64 * 8 + lane * 8;   // g=0, kt=0 base
    // g stride: 8*4*64*8 = 16384 ; kt stride: 64*8 = 512

    // ---- state init ----
    float h0v[4], h1v[4], c0v[4], c1v[4];
#pragma unroll
    for (int r4 = 0; r4 < 4; ++r4) {
        int row = qh * 4 + r4;
        int b = b0 + row, hj = w * 16 + ml;
        h0v[r4] = gv[(size_t)b * 128 + hj];
        h1v[r4] = gv[131072 + (size_t)b * 128 + hj];
        c0v[r4] = uv[(size_t)b * 128 + hj];
        c1v[r4] = uv[131072 + (size_t)b * 128 + hj];
        int ke = hj ^ ((row & 7) << 3);
        hA0[0][row * 128 + ke] = (f16)h0v[r4];
        hA1[0][row * 128 + ke] = (f16)h1v[r4];
    }
    int p = 0;
    __syncthreads();

    // A-frag read: lane reads A[m=ml][k = kt*32 + qh*8 .. +8] from swizzled tile
    auto readA = [&](const f16* base, int kt) -> f16x8 {
        int e = ml * 128 + (((kt << 5) + (qh << 3)) ^ ((ml & 7) << 3));
        return *(const f16x8*)(base + e);
    };

    auto lstm_step = [&](int t) {
        const f16* wf = (const f16*)(uintptr_t)wbase_s;   // LDS read: blocks LICM
        // ---------- layer 0: gates = h0 @ Whh0^T + xg0 ----------
        f32x4 C0, C1, C2, C3;
        {
            const float* xb = xgr + ((((size_t)blk * 10 + t) << 9) << 4);
            int coff = w * 16 + ml;
            C0 = *(const f32x4*)(xb + ((coff      ) << 4) + qh * 4);
            C1 = *(const f32x4*)(xb + ((coff + 128) << 4) + qh * 4);
            C2 = *(const f32x4*)(xb + ((coff + 256) << 4) + qh * 4);
            C3 = *(const f32x4*)(xb + ((coff + 384) << 4) + qh * 4);
        }
        // stream Whh0 frags (16 x dwordx4 from L2)
        f16x8 F0[4][4];
#pragma unroll
        for (int kt = 0; kt < 4; ++kt)
#pragma unroll
            for (int g = 0; g < 4; ++g)
                F0[kt][g] = *(const f16x8*)(wf + fo + g * 16384 + kt * 512);
        const f16* h0p = &hA0[p][0];
#pragma unroll
        for (int kt = 0; kt < 4; ++kt) {
            f16x8 a = readA(h0p, kt);
            C0 = MFMA16(a, F0[kt][0], C0);
            C1 = MFMA16(a, F0[kt][1], C1);
            C2 = MFMA16(a, F0[kt][2], C2);
            C3 = MFMA16(a, F0[kt][3], C3);
        }
        // stream Wih1 frags early (used right after the barrier)
        f16x8 F1[4][4];
#pragma unroll
        for (int kt = 0; kt < 4; ++kt)
#pragma unroll
            for (int g = 0; g < 4; ++g)
                F1[kt][g] = *(const f16x8*)(wf + 65536 + fo + g * 16384 + kt * 512);
        f16* h0n = &hA0[p ^ 1][0];
#pragma unroll
        for (int r4 = 0; r4 < 4; ++r4) {
            float cn = sigf(C1[r4]) * c0v[r4] + sigf(C0[r4]) * tanhfast(C2[r4]);
            float hn = sigf(C3[r4]) * tanhfast(cn);
            c0v[r4] = cn; h0v[r4] = hn;
            int row = qh * 4 + r4;
            h0n[row * 128 + ((w * 16 + ml) ^ ((row & 7) << 3))] = (f16)hn;
        }
        __syncthreads();
        // ---------- layer 1: gates = h0new @ Wih1^T + h1 @ Whh1^T + bias1 ----------
        C0 = f32x4{bs1v[0], bs1v[0], bs1v[0], bs1v[0]};
        C1 = f32x4{bs1v[1], bs1v[1], bs1v[1], bs1v[1]};
        C2 = f32x4{bs1v[2], bs1v[2], bs1v[2], bs1v[2]};
        C3 = f32x4{bs1v[3], bs1v[3], bs1v[3], bs1v[3]};
#pragma unroll
        for (int kt = 0; kt < 4; ++kt) {
            f16x8 a = readA(h0n, kt);
            C0 = MFMA16(a, F1[kt][0], C0);
            C1 = MFMA16(a, F1[kt][1], C1);
            C2 = MFMA16(a, F1[kt][2], C2);
            C3 = MFMA16(a, F1[kt][3], C3);
        }
        // stream Whh1 frags
        f16x8 F2[4][4];
#pragma unroll
        for (int kt = 0; kt < 4; ++kt)
#pragma unroll
            for (int g = 0; g < 4; ++g)
                F2[kt][g] = *(const f16x8*)(wf + 131072 + fo + g * 16384 + kt * 512);
        const f16* h1p = &hA1[p][0];
#pragma unroll
        for (int kt = 0; kt < 4; ++kt) {
            f16x8 a = readA(h1p, kt);
            C0 = MFMA16(a, F2[kt][0], C0);
            C1 = MFMA16(a, F2[kt][1], C1);
            C2 = MFMA16(a, F2[kt][2], C2);
            C3 = MFMA16(a, F2[kt][3], C3);
        }
        f16* h1n = &hA1[p ^ 1][0];
#pragma unroll
        for (int r4 = 0; r4 < 4; ++r4) {
            float cn = sigf(C1[r4]) * c1v[r4] + sigf(C0[r4]) * tanhfast(C2[r4]);
            float hn = sigf(C3[r4]) * tanhfast(cn);
            c1v[r4] = cn; h1v[r4] = hn;
            int row = qh * 4 + r4;
            h1n[row * 128 + ((w * 16 + ml) ^ ((row & 7) << 3))] = (f16)hn;
        }
        p ^= 1;
        __syncthreads();
    };

    for (int r = 0; r < 10; ++r) {
        for (int hist = 0; hist <= r; ++hist) {
            const int t0 = (hist <= 1) ? 0 : hist;  // quirk: hist==1 reruns full prefix
            for (int t = t0; t <= r; ++t) lstm_step(t);
#pragma unroll
            for (int r4 = 0; r4 < 4; ++r4) {   // Ms[hist] = h1
                int row = qh * 4 + r4;
                Msh[hist][row * 128 + ((w * 16 + ml) ^ ((row & 7) << 3))] = (f16)h1v[r4];
            }
        }
        __syncthreads();

        // ---------------- attention for round r ----------------
        {   // K rows (all 8 waves, n-tile = w), then Q
            f16x8 Bk[4];
#pragma unroll
            for (int kt = 0; kt < 4; ++kt) Bk[kt] = *(const f16x8*)(Wkf + (((w * 4 + kt) * 64 + lane) << 3));
            for (int kk = 0; kk <= r; ++kk) {
                f32x4 C = f32x4{bkv, bkv, bkv, bkv};
#pragma unroll
                for (int kt = 0; kt < 4; ++kt) C = MFMA16(readA(&Msh[kk][0], kt), Bk[kt], C);
#pragma unroll
                for (int r4 = 0; r4 < 4; ++r4) Kms[kk][(qh * 4 + r4) * 136 + w * 16 + ml] = (f16)C[r4];
            }
            f16x8 Bq[4];
#pragma unroll
            for (int kt = 0; kt < 4; ++kt) Bq[kt] = *(const f16x8*)(Wqf + (((w * 4 + kt) * 64 + lane) << 3));
            f32x4 C = f32x4{bqv, bqv, bqv, bqv};
#pragma unroll
            for (int kt = 0; kt < 4; ++kt) C = MFMA16(readA(&Msh[r][0], kt), Bq[kt], C);
#pragma unroll
            for (int r4 = 0; r4 < 4; ++r4) qsm[(qh * 4 + r4) * 132 + w * 16 + ml] = C[r4];
        }
        __syncthreads();
        // raw scores: thread per (row, kk)
        if (tid < 16 * (r + 1)) {
            int row = tid & 15, kk = tid >> 4;
            const float* qp = qsm + row * 132;
            const f16* kp = &Kms[kk][row * 136];
            float pacc = 0.f;
            for (int k = 0; k < 128; ++k) pacc += qp[k] * (float)kp[k];
            scs[row][kk] = pacc * 0.088388347648318447f;   // 1/sqrt(128)
        }
        __syncthreads();
        if (tid < 16) {   // softmax per row, probs in place
            float mx = -3.4e38f;
            for (int kk = 0; kk <= r; ++kk) mx = fmaxf(mx, scs[tid][kk]);
            float sum = 0.f;
            for (int kk = 0; kk <= r; ++kk) sum += __expf(scs[tid][kk] - mx);
            float inv = 1.0f / sum;
            for (int kk = 0; kk <= r; ++kk) scs[tid][kk] = __expf(scs[tid][kk] - mx) * inv;
        }
        __syncthreads();
        if (tid < 160) {  // attention output with -1 padding
            int row = tid / 10, jp = tid - row * 10;
            out[OFF_ATT + (size_t)(b0 + row) * 100 + (size_t)r * 10 + jp] = (jp <= r) ? scs[row][jp] : -1.0f;
        }
        // ---- V head: u = relu(Ms @ Wo1^T + bo1), v = u @ Wo2^T + bo2, logsoftmax ----
        float oa0 = 0.f, oa1 = 0.f;
        f16x8 Bo[4];
        if (w < 4) {
#pragma unroll
            for (int kt = 0; kt < 4; ++kt) Bo[kt] = *(const f16x8*)(Wo1f + (((w * 4 + kt) * 64 + lane) << 3));
        }
        for (int kk = 0; kk <= r; ++kk) {
            if (w < 4) {
                f32x4 C = f32x4{bo1v, bo1v, bo1v, bo1v};
#pragma unroll
                for (int kt = 0; kt < 4; ++kt) C = MFMA16(readA(&Msh[kk][0], kt), Bo[kt], C);
#pragma unroll
                for (int r4 = 0; r4 < 4; ++r4) us[(qh * 4 + r4) * 68 + w * 16 + ml] = fmaxf(C[r4], 0.f);
            }
            __syncthreads();
            if (tid < 16) {
                float v0 = wo2s[128], v1 = wo2s[129];
                const float* up = us + tid * 68;
                for (int k = 0; k < 64; ++k) {
                    float uu = up[k];
                    v0 = fmaf(uu, wo2s[k], v0);
                    v1 = fmaf(uu, wo2s[64 + k], v1);
                }
                float mv = fmaxf(v0, v1);
                float lse = mv + __logf(__expf(v0 - mv) + __expf(v1 - mv));
                float pp = scs[tid][kk];
                oa0 = fmaf(pp, v0 - lse, oa0);
                oa1 = fmaf(pp, v1 - lse, oa1);
            }
            __syncthreads();
        }
        if (tid < 16) {
            out[(size_t)(b0 + tid) * 20 + r * 2 + 0] = oa0;
            out[(size_t)(b0 + tid) * 20 + r * 2 + 1] = oa1;
        }
    }

    // final h, c (f32 register copies)
#pragma unroll
    for (int r4 = 0; r4 < 4; ++r4) {
        int b = b0 + qh * 4 + r4, hj = w * 16 + ml;
        out[OFF_H + (size_t)b * 128 + hj]          = h0v[r4];
        out[OFF_H + 131072 + (size_t)b * 128 + hj] = h1v[r4];
        out[OFF_C + (size_t)b * 128 + hj]          = c0v[r4];
        out[OFF_C + 131072 + (size_t)b * 128 + hj] = c1v[r4];
    }
}

// ---------------- launch ----------------
extern "C" void kernel_launch(void* const* d_in, const int* in_sizes, int n_in,
                              void* d_out, int out_size, void* d_ws, size_t ws_size,
                              hipStream_t stream) {
    const float* input_vec = (const float*)d_in[0];
    const float* gv    = (const float*)d_in[1];
    const float* uv    = (const float*)d_in[2];
    const float* W_in1 = (const float*)d_in[3];
    const float* b_in1 = (const float*)d_in[4];
    const float* W_in2 = (const float*)d_in[5];
    const float* b_in2 = (const float*)d_in[6];
    const float* Wq    = (const float*)d_in[7];
    const float* bq    = (const float*)d_in[8];
    const float* Wk    = (const float*)d_in[9];
    const float* bk    = (const float*)d_in[10];
    const float* Wih   = (const float*)d_in[11];
    const float* Whh   = (const float*)d_in[12];
    const float* bih   = (const float*)d_in[13];
    const float* bhh   = (const float*)d_in[14];
    const float* Wo1   = (const float*)d_in[15];
    const float* bo1   = (const float*)d_in[16];
    const float* Wo2   = (const float*)d_in[17];
    const float* bo2   = (const float*)d_in[18];
    float* out = (float*)d_out;
    float* ws  = (float*)d_ws;

    // workspace layout (float units)
    float* tmp1    = ws + 0;           // [10240][1024] (dead after gemm2)
    float* xg0     = ws + 0;           // [10240][512]  (gemm3 out, over tmp1)
    float* xgr     = ws + 5242880;     // [64][10][512][16] (inside old tmp1 tail)
    float* lstm_in = ws + 10485760;    // [10240][128]
    f16*   Wf      = (f16*)(ws + 11796480);   // 3 x 65536 f16
    f16*   Wqf     = (f16*)(ws + 11894784);   // 16384 f16
    f16*   Wkf     = (f16*)(ws + 11902976);
    f16*   Wo1f    = (f16*)(ws + 11911168);   // 8192 f16
    float* bias1c  = ws + 11915264;    // [512]
    float* bias0c  = ws + 11915776;    // [512]

    // weight fragment packing + bias combine
    pack_frag_k<<<256, 256, 0, stream>>>(Whh,          Wf,           512, 128); // Whh0
    pack_frag_k<<<256, 256, 0, stream>>>(Wih + 65536,  Wf + 65536,   512, 128); // Wih1
    pack_frag_k<<<256, 256, 0, stream>>>(Whh + 65536,  Wf + 131072,  512, 128); // Whh1
    pack_frag_k<<<64,  256, 0, stream>>>(Wq,  Wqf,  128, 128);
    pack_frag_k<<<64,  256, 0, stream>>>(Wk,  Wkf,  128, 128);
    pack_frag_k<<<32,  256, 0, stream>>>(Wo1, Wo1f, 64,  128);
    bias_comb_k<<<2, 256, 0, stream>>>(bih, bhh, bias0c, bias1c);

    // input MLP + layer-0 input-gate precompute (fp32), then frag-layout reshape
    gemm_bias_act_k<<<dim3(16, 160), 256, 0, stream>>>(input_vec, W_in1, b_in1, tmp1, 10240, 1024, 512, 1);
    gemm_bias_act_k<<<dim3(2, 160), 256, 0, stream>>>(tmp1, W_in2, b_in2, lstm_in, 10240, 128, 1024, 1);
    gemm_bias_act_k<<<dim3(8, 160), 256, 0, stream>>>(lstm_in, Wih, bias0c, xg0, 10240, 512, 128, 0);
    reshape_xg_k<<<20480, 256, 0, stream>>>(xg0, xgr);

    recurrent_mfma_k<<<64, 512, 0, stream>>>(xgr, Wf, bias1c,
                                             Wqf, bq, Wkf, bk, Wo1f, bo1, Wo2, bo2,
                                             gv, uv, out);
}